// Round 21
// baseline (748.139 us; speedup 1.0000x reference)
//
#include <hip/hip_runtime.h>

#define NODE_DIM 256
#define HIDDEN 64
#define NUM_REL 10

#define FMA4(A, S, W) do { \
    (A).x = fmaf((S), (W).x, (A).x); \
    (A).y = fmaf((S), (W).y, (A).y); \
    (A).z = fmaf((S), (W).z, (A).z); \
    (A).w = fmaf((S), (W).w, (A).w); } while (0)

#define ELEM(V, I) ((I) == 0 ? (V).x : (I) == 1 ? (V).y : (I) == 2 ? (V).z : (V).w)

// AGPR-denial fence: emits NOTHING and creates no data deps (no outputs used,
// no "memory" clobber -> loads/VALU schedule freely across it), but any value
// parked in a0..a63 cannot live across it. Placed in each chunk iteration it
// forces the 64 accumulators into architectural VGPRs, eliminating the
// v_accvgpr shuttle that costs ~50% extra VALU work (R17-R20, VGPR_Count=48).
#define NO_AGPR() asm("" ::: \
    "a0","a1","a2","a3","a4","a5","a6","a7", \
    "a8","a9","a10","a11","a12","a13","a14","a15", \
    "a16","a17","a18","a19","a20","a21","a22","a23", \
    "a24","a25","a26","a27","a28","a29","a30","a31", \
    "a32","a33","a34","a35","a36","a37","a38","a39", \
    "a40","a41","a42","a43","a44","a45","a46","a47", \
    "a48","a49","a50","a51","a52","a53","a54","a55", \
    "a56","a57","a58","a59","a60","a61","a62","a63")

// Edge kernel: R20 dataflow (16 KB per-thread LDS scratch, 4-quad chunks,
// each Hc line fetched once) + NO_AGPR fence per chunk. Chain order per
// output element unchanged: k ascending over W3 rows 64..127, +b3 after,
// relu, j-ascending logits, +b4 -> bit-identical to np.
__global__ __launch_bounds__(256, 4) void edge_kernel(
    const int* __restrict__ ei,
    const float* __restrict__ H, const float* __restrict__ A,
    const float* __restrict__ W3, const float* __restrict__ b3,
    const float* __restrict__ W4, const float* __restrict__ b4,
    float* __restrict__ out_type, float* __restrict__ out_probs, int E)
{
    __shared__ float4 HcS[256 * 4];   // 16 KB: per-thread 4-quad scratch

    const int tid = threadIdx.x;
    const int e = blockIdx.x * 256 + tid;
    const bool valid = (e < E);
    const int sw = tid & 3;
    float4* myscr = &HcS[tid * 4];

    const int c = valid ? ei[E + e] : 0;
    const int r = valid ? ei[e] : 0;
    const float4* src = (const float4*)(H + (size_t)c * 64);
    const float4* Ar  = (const float4*)(A + (size_t)r * 64);

    // stage chunk 0: Hc quads 0..3
    #pragma unroll
    for (int q = 0; q < 4; ++q) myscr[q ^ sw] = src[q];

    // seed 16 acc quads from the A chain prefix (one-shot gather)
    float4 acc[16];
    #pragma unroll
    for (int j = 0; j < 16; ++j) acc[j] = Ar[j];

    const float* W3b = W3 + 64 * 64;

    #pragma unroll 1
    for (int ch = 0; ch < 4; ++ch) {
        NO_AGPR();   // accs must be in arch VGPRs at every iteration boundary
        // consume chunk ch: k4 = 4*ch .. 4*ch+3 (k ascending, 1024 FMAs)
        #pragma unroll 1
        for (int k4l = 0; k4l < 4; ++k4l) {
            NO_AGPR();
            const float4 hv = myscr[k4l ^ sw];
            const int k4 = ch * 4 + k4l;
            #pragma unroll
            for (int i = 0; i < 4; ++i) {
                const float s = ELEM(hv, i);
                const float* w = W3b + (size_t)(k4 * 4 + i) * 64;
                #pragma unroll
                for (int j = 0; j < 16; ++j) {
                    float4 wv = *(const float4*)(w + 4 * j);
                    FMA4(acc[j], s, wv);
                }
            }
        }
        // stage next chunk (same L2 lines as this row, each fetched once)
        if (ch < 3) {
            #pragma unroll
            for (int q = 0; q < 4; ++q)
                myscr[q ^ sw] = src[(ch + 1) * 4 + q];
        }
    }

    // + b3, relu (j ascending)
    #pragma unroll
    for (int j = 0; j < 16; ++j) {
        float4 bv = *(const float4*)(b3 + 4 * j);
        acc[j].x = fmaxf(acc[j].x + bv.x, 0.f);
        acc[j].y = fmaxf(acc[j].y + bv.y, 0.f);
        acc[j].z = fmaxf(acc[j].z + bv.z, 0.f);
        acc[j].w = fmaxf(acc[j].w + bv.w, 0.f);
    }

    // logits = (hid @ W4) + b4, j ascending
    float lg[NUM_REL];
    #pragma unroll
    for (int j = 0; j < NUM_REL; ++j) lg[j] = 0.0f;
    #pragma unroll
    for (int jq = 0; jq < 16; ++jq) {
        #pragma unroll
        for (int i = 0; i < 4; ++i) {
            const float s = ELEM(acc[jq], i);
            const float* w = W4 + (size_t)(jq * 4 + i) * NUM_REL;
            #pragma unroll
            for (int j = 0; j < NUM_REL; ++j) lg[j] = fmaf(s, w[j], lg[j]);
        }
    }

    if (!valid) return;

    #pragma unroll
    for (int j = 0; j < NUM_REL; ++j) lg[j] += b4[j];

    // argmax, first occurrence
    int best = 0;
    float bm = lg[0];
    #pragma unroll
    for (int j = 1; j < NUM_REL; ++j)
        if (lg[j] > bm) { bm = lg[j]; best = j; }

    // softmax fp32
    float p[NUM_REL];
    float sum = 0.0f;
    #pragma unroll
    for (int j = 0; j < NUM_REL; ++j) {
        p[j] = expf(lg[j] - bm);
        sum += p[j];
    }
    float inv = 1.0f / sum;

    out_type[e] = (float)best;
    float* op = out_probs + (size_t)e * NUM_REL;
    #pragma unroll
    for (int j = 0; j < NUM_REL; ++j) op[j] = p[j] * inv;
}

// Node pipeline: R17 verbatim (~95 us). Block = 4 waves x 64 lanes; lane =
// node, wave = j-slice via readfirstlane -> SGPR -> s_load weights. h1/h
// handed between layers via LDS [64][65]. Per-element np/BLAS chain: acc=0,
// k ascending fmaf over FULL K, bias AFTER, relu -> bit-identical.
__global__ __launch_bounds__(256, 4) void node_kernel(
    const float* __restrict__ x,
    const float* __restrict__ W1, const float* __restrict__ b1,
    const float* __restrict__ W2, const float* __restrict__ b2,
    const float* __restrict__ W3,
    float* __restrict__ Hout, float* __restrict__ Aout, int N)
{
    __shared__ float h1s[64][65];
    __shared__ float hs[64][65];

    const int tid  = threadIdx.x;
    const int lane = tid & 63;
    const int jb   = __builtin_amdgcn_readfirstlane((tid >> 6) << 4);
    const int n    = blockIdx.x * 64 + lane;
    const bool valid = (n < N);
    const int nc   = valid ? n : (N - 1);

    // ---- L1 slice: h1[jb..jb+16) = relu((x@W1) + b1) ----
    float4 a0 = make_float4(0.f, 0.f, 0.f, 0.f);
    float4 a1 = a0, a2 = a0, a3 = a0;

    const float4* xr = (const float4*)(x + (size_t)nc * NODE_DIM);
    #pragma unroll 1
    for (int k4 = 0; k4 < NODE_DIM / 4; ++k4) {
        float4 xv = xr[k4];
        #pragma unroll
        for (int i = 0; i < 4; ++i) {
            const float s = ELEM(xv, i);
            const float4* w = (const float4*)(W1 + (size_t)(k4 * 4 + i) * 64 + jb);
            float4 w0 = w[0], w1 = w[1], w2 = w[2], w3 = w[3];
            FMA4(a0, s, w0); FMA4(a1, s, w1);
            FMA4(a2, s, w2); FMA4(a3, s, w3);
        }
    }
    {
        const float4* bv = (const float4*)(b1 + jb);
        float4 b0 = bv[0], b1v = bv[1], b2v = bv[2], b3v = bv[3];
        float* d = &h1s[lane][jb];
        d[0]  = fmaxf(a0.x + b0.x, 0.f);  d[1]  = fmaxf(a0.y + b0.y, 0.f);
        d[2]  = fmaxf(a0.z + b0.z, 0.f);  d[3]  = fmaxf(a0.w + b0.w, 0.f);
        d[4]  = fmaxf(a1.x + b1v.x, 0.f); d[5]  = fmaxf(a1.y + b1v.y, 0.f);
        d[6]  = fmaxf(a1.z + b1v.z, 0.f); d[7]  = fmaxf(a1.w + b1v.w, 0.f);
        d[8]  = fmaxf(a2.x + b2v.x, 0.f); d[9]  = fmaxf(a2.y + b2v.y, 0.f);
        d[10] = fmaxf(a2.z + b2v.z, 0.f); d[11] = fmaxf(a2.w + b2v.w, 0.f);
        d[12] = fmaxf(a3.x + b3v.x, 0.f); d[13] = fmaxf(a3.y + b3v.y, 0.f);
        d[14] = fmaxf(a3.z + b3v.z, 0.f); d[15] = fmaxf(a3.w + b3v.w, 0.f);
    }
    __syncthreads();

    // ---- L2 slice: h[jb..jb+16) = (h1@W2) + b2 ----
    a0 = make_float4(0.f, 0.f, 0.f, 0.f); a1 = a0; a2 = a0; a3 = a0;
    #pragma unroll 1
    for (int k = 0; k < 64; ++k) {
        const float s = h1s[lane][k];
        const float4* w = (const float4*)(W2 + (size_t)k * 64 + jb);
        float4 w0 = w[0], w1 = w[1], w2 = w[2], w3 = w[3];
        FMA4(a0, s, w0); FMA4(a1, s, w1);
        FMA4(a2, s, w2); FMA4(a3, s, w3);
    }
    {
        const float4* bv = (const float4*)(b2 + jb);
        float4 b0 = bv[0], b1v = bv[1], b2v = bv[2], b3v = bv[3];
        float4 r0, r1, r2, r3;
        r0.x = a0.x + b0.x;  r0.y = a0.y + b0.y;  r0.z = a0.z + b0.z;  r0.w = a0.w + b0.w;
        r1.x = a1.x + b1v.x; r1.y = a1.y + b1v.y; r1.z = a1.z + b1v.z; r1.w = a1.w + b1v.w;
        r2.x = a2.x + b2v.x; r2.y = a2.y + b2v.y; r2.z = a2.z + b2v.z; r2.w = a2.w + b2v.w;
        r3.x = a3.x + b3v.x; r3.y = a3.y + b3v.y; r3.z = a3.z + b3v.z; r3.w = a3.w + b3v.w;
        float* d = &hs[lane][jb];
        d[0]  = r0.x; d[1]  = r0.y; d[2]  = r0.z; d[3]  = r0.w;
        d[4]  = r1.x; d[5]  = r1.y; d[6]  = r1.z; d[7]  = r1.w;
        d[8]  = r2.x; d[9]  = r2.y; d[10] = r2.z; d[11] = r2.w;
        d[12] = r3.x; d[13] = r3.y; d[14] = r3.z; d[15] = r3.w;
        if (valid) {
            float4* g = (float4*)(Hout + (size_t)n * 64 + jb);
            g[0] = r0; g[1] = r1; g[2] = r2; g[3] = r3;
        }
    }
    __syncthreads();

    // ---- L3 row-half partial slice: A[jb..jb+16) = h @ W3[0:64], no bias ----
    a0 = make_float4(0.f, 0.f, 0.f, 0.f); a1 = a0; a2 = a0; a3 = a0;
    #pragma unroll 1
    for (int k = 0; k < 64; ++k) {
        const float s = hs[lane][k];
        const float4* w = (const float4*)(W3 + (size_t)k * 64 + jb);
        float4 w0 = w[0], w1 = w[1], w2 = w[2], w3 = w[3];
        FMA4(a0, s, w0); FMA4(a1, s, w1);
        FMA4(a2, s, w2); FMA4(a3, s, w3);
    }
    if (valid) {
        float4* g = (float4*)(Aout + (size_t)n * 64 + jb);
        g[0] = a0; g[1] = a1; g[2] = a2; g[3] = a3;
    }
}

extern "C" void kernel_launch(void* const* d_in, const int* in_sizes, int n_in,
                              void* d_out, int out_size, void* d_ws, size_t ws_size,
                              hipStream_t stream)
{
    const float* x  = (const float*)d_in[0];
    const int*   ei = (const int*)d_in[1];
    const float* W1 = (const float*)d_in[2];
    const float* b1 = (const float*)d_in[3];
    const float* W2 = (const float*)d_in[4];
    const float* b2 = (const float*)d_in[5];
    const float* W3 = (const float*)d_in[6];
    const float* b3 = (const float*)d_in[7];
    const float* W4 = (const float*)d_in[8];
    const float* b4 = (const float*)d_in[9];

    int N = in_sizes[0] / NODE_DIM;   // 100000
    int E = in_sizes[1] / 2;          // 1600000

    // ws: H [N*64] f32 | A [N*64] f32   (51.2 MB total)
    float* H = (float*)d_ws;
    float* A = H + (size_t)N * 64;

    int nb = (N + 63) / 64;
    int eb = (E + 255) / 256;

    float* out_type  = (float*)d_out;
    float* out_probs = (float*)d_out + E;

    hipLaunchKernelGGL(node_kernel, dim3(nb), dim3(256), 0, stream,
                       x, W1, b1, W2, b2, W3, H, A, N);
    hipLaunchKernelGGL(edge_kernel, dim3(eb), dim3(256), 0, stream,
                       ei, H, A, W3, b3, W4, b4, out_type, out_probs, E);
}

// Round 22
// 311.988 us; speedup vs baseline: 2.3980x; 2.3980x over previous
//
#include <hip/hip_runtime.h>

#define NODE_DIM 256
#define HIDDEN 64
#define NUM_REL 10

#define FMA4(A, S, W) do { \
    (A).x = fmaf((S), (W).x, (A).x); \
    (A).y = fmaf((S), (W).y, (A).y); \
    (A).z = fmaf((S), (W).z, (A).z); \
    (A).w = fmaf((S), (W).w, (A).w); } while (0)

#define ELEM(V, I) ((I) == 0 ? (V).x : (I) == 1 ? (V).y : (I) == 2 ? (V).z : (V).w)

// Edge kernel: R13 dataflow (32 KB per-thread LDS scratch, Hc row staged in
// two 8-quad chunks, each 128B line fetched once) with two codegen levers vs
// R17-R21's 213us AGPR-shuttle form:
//   1. SCALAR float acc[64] (the only form that ever got VGPR~100 — R5),
//      not float4 acc[16] (which drew VGPR 52-56 shuttle allocations).
//   2. __launch_bounds__(256, 2): lifts the VGPR cap 128 -> 256 so the
//      allocator has no pressure incentive to park accs in AGPRs.
//      Occupancy is LDS-capped at 4 blocks/CU either way -> no cost.
// Math/chain order byte-identical to R13: k ascending over W3 rows 64..127,
// +b3 after, relu, j-ascending logits, +b4 -> bit-identical to np.
__global__ __launch_bounds__(256, 2) void edge_kernel(
    const int* __restrict__ ei,
    const float* __restrict__ H, const float* __restrict__ A,
    const float* __restrict__ W3, const float* __restrict__ b3,
    const float* __restrict__ W4, const float* __restrict__ b4,
    float* __restrict__ out_type, float* __restrict__ out_probs, int E)
{
    __shared__ float4 HcS[256 * 8];   // 32 KB: per-thread 8-quad scratch

    const int tid = threadIdx.x;
    const int e = blockIdx.x * 256 + tid;
    const bool valid = (e < E);
    const int sw = tid & 7;
    float4* myscr = &HcS[tid * 8];

    const int c = valid ? ei[E + e] : 0;
    const int r = valid ? ei[e] : 0;
    const float4* src = (const float4*)(H + (size_t)c * 64);
    const float4* Ar  = (const float4*)(A + (size_t)r * 64);

    // stage chunk 0: Hc quads 0..7
    #pragma unroll
    for (int q = 0; q < 8; ++q) myscr[q ^ sw] = src[q];

    // seed 64 SCALAR accumulators from the A chain prefix (one-shot gather)
    float acc[64];
    #pragma unroll
    for (int j4 = 0; j4 < 16; ++j4) {
        float4 v = Ar[j4];
        acc[4 * j4 + 0] = v.x; acc[4 * j4 + 1] = v.y;
        acc[4 * j4 + 2] = v.z; acc[4 * j4 + 3] = v.w;
    }

    const float* W3b = W3 + 64 * 64;

    // chunk 0: k4 = 0..7 (W3 rows 64..95, ascending)
    #pragma unroll 1
    for (int k4 = 0; k4 < 8; ++k4) {
        const float4 hv = myscr[k4 ^ sw];
        #pragma unroll
        for (int i = 0; i < 4; ++i) {
            const float s = ELEM(hv, i);
            const float* w = W3b + (size_t)(k4 * 4 + i) * 64;
            #pragma unroll
            for (int j4 = 0; j4 < 16; ++j4) {
                float4 wv = *(const float4*)(w + 4 * j4);
                acc[4 * j4 + 0] = fmaf(s, wv.x, acc[4 * j4 + 0]);
                acc[4 * j4 + 1] = fmaf(s, wv.y, acc[4 * j4 + 1]);
                acc[4 * j4 + 2] = fmaf(s, wv.z, acc[4 * j4 + 2]);
                acc[4 * j4 + 3] = fmaf(s, wv.w, acc[4 * j4 + 3]);
            }
        }
    }

    // restage chunk 1: Hc quads 8..15 (same L2 lines, fetched once)
    #pragma unroll
    for (int q = 0; q < 8; ++q) myscr[q ^ sw] = src[8 + q];

    // chunk 1: k4 = 8..15 (W3 rows 96..127, ascending)
    #pragma unroll 1
    for (int k4 = 8; k4 < 16; ++k4) {
        const float4 hv = myscr[(k4 - 8) ^ sw];
        #pragma unroll
        for (int i = 0; i < 4; ++i) {
            const float s = ELEM(hv, i);
            const float* w = W3b + (size_t)(k4 * 4 + i) * 64;
            #pragma unroll
            for (int j4 = 0; j4 < 16; ++j4) {
                float4 wv = *(const float4*)(w + 4 * j4);
                acc[4 * j4 + 0] = fmaf(s, wv.x, acc[4 * j4 + 0]);
                acc[4 * j4 + 1] = fmaf(s, wv.y, acc[4 * j4 + 1]);
                acc[4 * j4 + 2] = fmaf(s, wv.z, acc[4 * j4 + 2]);
                acc[4 * j4 + 3] = fmaf(s, wv.w, acc[4 * j4 + 3]);
            }
        }
    }

    // + b3, relu (j ascending)
    #pragma unroll
    for (int j = 0; j < 64; ++j)
        acc[j] = fmaxf(acc[j] + b3[j], 0.0f);

    // logits = (hid @ W4) + b4, j ascending
    float lg[NUM_REL];
    #pragma unroll
    for (int j = 0; j < NUM_REL; ++j) lg[j] = 0.0f;
    #pragma unroll
    for (int k = 0; k < 64; ++k) {
        const float s = acc[k];
        const float* wp = W4 + (size_t)k * NUM_REL;
        #pragma unroll
        for (int j = 0; j < NUM_REL; ++j) lg[j] = fmaf(s, wp[j], lg[j]);
    }

    if (!valid) return;

    #pragma unroll
    for (int j = 0; j < NUM_REL; ++j) lg[j] += b4[j];

    // argmax, first occurrence
    int best = 0;
    float bm = lg[0];
    #pragma unroll
    for (int j = 1; j < NUM_REL; ++j)
        if (lg[j] > bm) { bm = lg[j]; best = j; }

    // softmax fp32
    float p[NUM_REL];
    float sum = 0.0f;
    #pragma unroll
    for (int j = 0; j < NUM_REL; ++j) {
        p[j] = expf(lg[j] - bm);
        sum += p[j];
    }
    float inv = 1.0f / sum;

    out_type[e] = (float)best;
    float* op = out_probs + (size_t)e * NUM_REL;
    #pragma unroll
    for (int j = 0; j < NUM_REL; ++j) op[j] = p[j] * inv;
}

// Node pipeline: R17 verbatim (~95 us). Block = 4 waves x 64 lanes; lane =
// node, wave = j-slice via readfirstlane -> SGPR -> s_load weights. h1/h
// handed between layers via LDS [64][65]. Per-element np/BLAS chain: acc=0,
// k ascending fmaf over FULL K, bias AFTER, relu -> bit-identical.
__global__ __launch_bounds__(256, 4) void node_kernel(
    const float* __restrict__ x,
    const float* __restrict__ W1, const float* __restrict__ b1,
    const float* __restrict__ W2, const float* __restrict__ b2,
    const float* __restrict__ W3,
    float* __restrict__ Hout, float* __restrict__ Aout, int N)
{
    __shared__ float h1s[64][65];
    __shared__ float hs[64][65];

    const int tid  = threadIdx.x;
    const int lane = tid & 63;
    const int jb   = __builtin_amdgcn_readfirstlane((tid >> 6) << 4);
    const int n    = blockIdx.x * 64 + lane;
    const bool valid = (n < N);
    const int nc   = valid ? n : (N - 1);

    // ---- L1 slice: h1[jb..jb+16) = relu((x@W1) + b1) ----
    float4 a0 = make_float4(0.f, 0.f, 0.f, 0.f);
    float4 a1 = a0, a2 = a0, a3 = a0;

    const float4* xr = (const float4*)(x + (size_t)nc * NODE_DIM);
    #pragma unroll 1
    for (int k4 = 0; k4 < NODE_DIM / 4; ++k4) {
        float4 xv = xr[k4];
        #pragma unroll
        for (int i = 0; i < 4; ++i) {
            const float s = ELEM(xv, i);
            const float4* w = (const float4*)(W1 + (size_t)(k4 * 4 + i) * 64 + jb);
            float4 w0 = w[0], w1 = w[1], w2 = w[2], w3 = w[3];
            FMA4(a0, s, w0); FMA4(a1, s, w1);
            FMA4(a2, s, w2); FMA4(a3, s, w3);
        }
    }
    {
        const float4* bv = (const float4*)(b1 + jb);
        float4 b0 = bv[0], b1v = bv[1], b2v = bv[2], b3v = bv[3];
        float* d = &h1s[lane][jb];
        d[0]  = fmaxf(a0.x + b0.x, 0.f);  d[1]  = fmaxf(a0.y + b0.y, 0.f);
        d[2]  = fmaxf(a0.z + b0.z, 0.f);  d[3]  = fmaxf(a0.w + b0.w, 0.f);
        d[4]  = fmaxf(a1.x + b1v.x, 0.f); d[5]  = fmaxf(a1.y + b1v.y, 0.f);
        d[6]  = fmaxf(a1.z + b1v.z, 0.f); d[7]  = fmaxf(a1.w + b1v.w, 0.f);
        d[8]  = fmaxf(a2.x + b2v.x, 0.f); d[9]  = fmaxf(a2.y + b2v.y, 0.f);
        d[10] = fmaxf(a2.z + b2v.z, 0.f); d[11] = fmaxf(a2.w + b2v.w, 0.f);
        d[12] = fmaxf(a3.x + b3v.x, 0.f); d[13] = fmaxf(a3.y + b3v.y, 0.f);
        d[14] = fmaxf(a3.z + b3v.z, 0.f); d[15] = fmaxf(a3.w + b3v.w, 0.f);
    }
    __syncthreads();

    // ---- L2 slice: h[jb..jb+16) = (h1@W2) + b2 ----
    a0 = make_float4(0.f, 0.f, 0.f, 0.f); a1 = a0; a2 = a0; a3 = a0;
    #pragma unroll 1
    for (int k = 0; k < 64; ++k) {
        const float s = h1s[lane][k];
        const float4* w = (const float4*)(W2 + (size_t)k * 64 + jb);
        float4 w0 = w[0], w1 = w[1], w2 = w[2], w3 = w[3];
        FMA4(a0, s, w0); FMA4(a1, s, w1);
        FMA4(a2, s, w2); FMA4(a3, s, w3);
    }
    {
        const float4* bv = (const float4*)(b2 + jb);
        float4 b0 = bv[0], b1v = bv[1], b2v = bv[2], b3v = bv[3];
        float4 r0, r1, r2, r3;
        r0.x = a0.x + b0.x;  r0.y = a0.y + b0.y;  r0.z = a0.z + b0.z;  r0.w = a0.w + b0.w;
        r1.x = a1.x + b1v.x; r1.y = a1.y + b1v.y; r1.z = a1.z + b1v.z; r1.w = a1.w + b1v.w;
        r2.x = a2.x + b2v.x; r2.y = a2.y + b2v.y; r2.z = a2.z + b2v.z; r2.w = a2.w + b2v.w;
        r3.x = a3.x + b3v.x; r3.y = a3.y + b3v.y; r3.z = a3.z + b3v.z; r3.w = a3.w + b3v.w;
        float* d = &hs[lane][jb];
        d[0]  = r0.x; d[1]  = r0.y; d[2]  = r0.z; d[3]  = r0.w;
        d[4]  = r1.x; d[5]  = r1.y; d[6]  = r1.z; d[7]  = r1.w;
        d[8]  = r2.x; d[9]  = r2.y; d[10] = r2.z; d[11] = r2.w;
        d[12] = r3.x; d[13] = r3.y; d[14] = r3.z; d[15] = r3.w;
        if (valid) {
            float4* g = (float4*)(Hout + (size_t)n * 64 + jb);
            g[0] = r0; g[1] = r1; g[2] = r2; g[3] = r3;
        }
    }
    __syncthreads();

    // ---- L3 row-half partial slice: A[jb..jb+16) = h @ W3[0:64], no bias ----
    a0 = make_float4(0.f, 0.f, 0.f, 0.f); a1 = a0; a2 = a0; a3 = a0;
    #pragma unroll 1
    for (int k = 0; k < 64; ++k) {
        const float s = hs[lane][k];
        const float4* w = (const float4*)(W3 + (size_t)k * 64 + jb);
        float4 w0 = w[0], w1 = w[1], w2 = w[2], w3 = w[3];
        FMA4(a0, s, w0); FMA4(a1, s, w1);
        FMA4(a2, s, w2); FMA4(a3, s, w3);
    }
    if (valid) {
        float4* g = (float4*)(Aout + (size_t)n * 64 + jb);
        g[0] = a0; g[1] = a1; g[2] = a2; g[3] = a3;
    }
}

extern "C" void kernel_launch(void* const* d_in, const int* in_sizes, int n_in,
                              void* d_out, int out_size, void* d_ws, size_t ws_size,
                              hipStream_t stream)
{
    const float* x  = (const float*)d_in[0];
    const int*   ei = (const int*)d_in[1];
    const float* W1 = (const float*)d_in[2];
    const float* b1 = (const float*)d_in[3];
    const float* W2 = (const float*)d_in[4];
    const float* b2 = (const float*)d_in[5];
    const float* W3 = (const float*)d_in[6];
    const float* b3 = (const float*)d_in[7];
    const float* W4 = (const float*)d_in[8];
    const float* b4 = (const float*)d_in[9];

    int N = in_sizes[0] / NODE_DIM;   // 100000
    int E = in_sizes[1] / 2;          // 1600000

    // ws: H [N*64] f32 | A [N*64] f32   (51.2 MB total)
    float* H = (float*)d_ws;
    float* A = H + (size_t)N * 64;

    int nb = (N + 63) / 64;
    int eb = (E + 255) / 256;

    float* out_type  = (float*)d_out;
    float* out_probs = (float*)d_out + E;

    hipLaunchKernelGGL(node_kernel, dim3(nb), dim3(256), 0, stream,
                       x, W1, b1, W2, b2, W3, H, A, N);
    hipLaunchKernelGGL(edge_kernel, dim3(eb), dim3(256), 0, stream,
                       ei, H, A, W3, b3, W4, b4, out_type, out_probs, E);
}